// Round 8
// baseline (1324.852 us; speedup 1.0000x reference)
//
#include <hip/hip_runtime.h>

typedef _Float16 f16;
typedef _Float16 h2 __attribute__((ext_vector_type(2)));
typedef _Float16 h8 __attribute__((ext_vector_type(8)));
typedef _Float16 v8h __attribute__((ext_vector_type(8)));
typedef _Float16 v4h __attribute__((ext_vector_type(4)));
typedef float    f4 __attribute__((ext_vector_type(4)));
typedef float    v4f __attribute__((ext_vector_type(4)));
typedef float    f2 __attribute__((ext_vector_type(2)));

#define S_  256
#define B_  1024
#define D_  64
#define H_  128
#define Z_  32
#define BD_ (B_*D_)
#define NSTEP 514

__device__ __forceinline__ h8 ld8(const float* p) {   // 32B-aligned src
  f4 a = *(const f4*)p;
  f4 b = *(const f4*)(p + 4);
  h8 w;
  w[0]=(f16)a[0]; w[1]=(f16)a[1]; w[2]=(f16)a[2]; w[3]=(f16)a[3];
  w[4]=(f16)b[0]; w[5]=(f16)b[1]; w[6]=(f16)b[2]; w[7]=(f16)b[3];
  return w;
}

__device__ __forceinline__ float sigm(float x) { return 1.f / (1.f + __expf(-x)); }
__device__ __forceinline__ float tanh_(float x) {
  float e = __expf(-2.f * fabsf(x));
  float t = (1.f - e) / (1.f + e);
  return copysignf(t, x);
}

// ---------------------------------------------------------------------------
// GRU round-8: 64 blocks x 8 WAVES (512 thr) -> 2 waves/SIMD (latency hiding
// at the SIMD scheduler level; was 1 wave/SIMD). Wave w owns neuron rows
// w*16..w*16+15 of ALL 3 gates (gate combine lane-local). Per wave/step:
// 18 MFMA (4 indep chains, max depth 6), 4-neuron gate VALU (half the
// exp/rcp chain of the 4-wave version), 4 ds_read_b128, 1 ds_write_b64,
// ONE barrier. hB double-buffered [16][136] f16.
// ---------------------------------------------------------------------------
__global__ __launch_bounds__(512, 1) void gru_mfma_kernel(
    const float* __restrict__ xs, const float* __restrict__ Wih,
    const float* __restrict__ Whh, const float* __restrict__ bih,
    const float* __restrict__ bhh, float* __restrict__ hT)
{
  __shared__ f16 hB[2][16][136];   // [buf][batch][h + pad8]

  const int t    = threadIdx.x;
  const int wid  = t >> 6;         // 0..7
  const int lane = t & 63;
  const int lr = lane & 15;        // A row / batch col
  const int lg = lane >> 4;        // k-group / C row-group
  const int r0 = blockIdx.x * 16;

  // ---- weight A-frags: neuron row nr = wid*16 + lr, k = ks*32 + lg*8 + j
  const int nr = wid*16 + lr;
  v8h whR[4], whZ[4], whN[4], wiR[2], wiZ[2], wiN[2];
  #pragma unroll
  for (int ks = 0; ks < 4; ++ks) {
    whR[ks] = ld8(Whh + (      nr)*H_ + ks*32 + lg*8);
    whZ[ks] = ld8(Whh + (128 + nr)*H_ + ks*32 + lg*8);
    whN[ks] = ld8(Whh + (256 + nr)*H_ + ks*32 + lg*8);
  }
  #pragma unroll
  for (int ks = 0; ks < 2; ++ks) {
    wiR[ks] = ld8(Wih + (      nr)*D_ + ks*32 + lg*8);
    wiZ[ks] = ld8(Wih + (128 + nr)*D_ + ks*32 + lg*8);
    wiN[ks] = ld8(Wih + (256 + nr)*D_ + ks*32 + lg*8);
  }
  // ---- per-lane gate biases (neurons wid*16 + lg*4 + i)
  const int nb = wid*16 + lg*4;
  const v4f birh = *(const v4f*)&bih[nb]     + *(const v4f*)&bhh[nb];
  const v4f bizh = *(const v4f*)&bih[128+nb] + *(const v4f*)&bhh[128+nb];
  const v4f binv = *(const v4f*)&bih[256+nb];
  const v4f bhnv = *(const v4f*)&bhh[256+nb];

  for (int i = t; i < 16*136; i += 512) ((f16*)hB[0])[i] = (f16)0.f;
  v4f hm = {0.f, 0.f, 0.f, 0.f};    // fp32 h master
  const v4f zero4 = {0.f, 0.f, 0.f, 0.f};

  // x B-frags for step 0 (x_rev[0] = xs[S-1])
  v8h bx0 = ld8(xs + (S_-1)*BD_ + (r0+lr)*D_ + lg*8);
  v8h bx1 = ld8(xs + (S_-1)*BD_ + (r0+lr)*D_ + 32 + lg*8);
  __syncthreads();

  int p = 0;
  #pragma unroll 1
  for (int s = 0; s < S_; ++s) {
    v8h nx0 = bx0, nx1 = bx1;
    if (s < S_-1) {
      const float* xp = xs + (S_-2-s)*BD_ + (r0+lr)*D_;
      nx0 = ld8(xp + lg*8);
      nx1 = ld8(xp + 32 + lg*8);
    }
    v8h bh[4];
    #pragma unroll
    for (int ks = 0; ks < 4; ++ks)
      bh[ks] = *(const v8h*)&hB[p][lr][ks*32 + lg*8];

    v4f ar  = __builtin_amdgcn_mfma_f32_16x16x32_f16(wiR[0], bx0, zero4, 0,0,0);
    v4f az  = __builtin_amdgcn_mfma_f32_16x16x32_f16(wiZ[0], bx0, zero4, 0,0,0);
    v4f anx = __builtin_amdgcn_mfma_f32_16x16x32_f16(wiN[0], bx0, zero4, 0,0,0);
    ar  = __builtin_amdgcn_mfma_f32_16x16x32_f16(wiR[1], bx1, ar,  0,0,0);
    az  = __builtin_amdgcn_mfma_f32_16x16x32_f16(wiZ[1], bx1, az,  0,0,0);
    anx = __builtin_amdgcn_mfma_f32_16x16x32_f16(wiN[1], bx1, anx, 0,0,0);
    v4f anh = zero4;
    #pragma unroll
    for (int ks = 0; ks < 4; ++ks) {
      ar  = __builtin_amdgcn_mfma_f32_16x16x32_f16(whR[ks], bh[ks], ar,  0,0,0);
      az  = __builtin_amdgcn_mfma_f32_16x16x32_f16(whZ[ks], bh[ks], az,  0,0,0);
      anh = __builtin_amdgcn_mfma_f32_16x16x32_f16(whN[ks], bh[ks], anh, 0,0,0);
    }
    v4h o;
    #pragma unroll
    for (int i = 0; i < 4; ++i) {
      float r  = sigm(ar[i] + birh[i]);
      float zg = sigm(az[i] + bizh[i]);
      float n  = tanh_(anx[i] + binv[i] + r*(anh[i] + bhnv[i]));
      hm[i] = (1.f - zg)*n + zg*hm[i];
      o[i] = (f16)hm[i];
    }
    *(v4h*)&hB[p^1][lr][wid*16 + lg*4] = o;
    __syncthreads();
    p ^= 1;
    bx0 = nx0; bx1 = nx1;
  }

  *(v4f*)&hT[(r0+lr)*H_ + wid*16 + lg*4] = hm;
}

// ---------------------------------------------------------------------------
// Encoder head (unchanged; tiny): 256 blocks x 4 rows.
// ---------------------------------------------------------------------------
__global__ __launch_bounds__(256) void enc_kernel(
    const float* __restrict__ hT, const float* __restrict__ encW,
    const float* __restrict__ encB, const float* __restrict__ qW,
    const float* __restrict__ qB, const float* __restrict__ eps,
    const float* __restrict__ pm, const float* __restrict__ pls,
    float* __restrict__ z0, float* __restrict__ out)
{
  __shared__ float hTl[4][128];
  __shared__ float ctx[4][64];
  __shared__ float ql[4][64];
  const int t = threadIdx.x;
  const int b0 = blockIdx.x * 4;
  const int lb = t >> 6, j = t & 63;

  for (int i = t; i < 512; i += 256) hTl[i>>7][i&127] = hT[b0*H_ + i];
  __syncthreads();

  float acc = encB[j];
  #pragma unroll
  for (int k = 0; k < 128; k += 4) {
    f4 w = *(const f4*)&encW[j*128 + k];
    acc += hTl[lb][k]*w[0] + hTl[lb][k+1]*w[1] + hTl[lb][k+2]*w[2] + hTl[lb][k+3]*w[3];
  }
  ctx[lb][j] = acc;
  __syncthreads();

  float q = qB[j];
  #pragma unroll
  for (int k = 0; k < 64; k += 4) {
    f4 w = *(const f4*)&qW[j*64 + k];
    q += ctx[lb][k]*w[0] + ctx[lb][k+1]*w[1] + ctx[lb][k+2]*w[2] + ctx[lb][k+3]*w[3];
  }
  ql[lb][j] = q;
  __syncthreads();

  float kl = 0.f;
  if (j < 32) {
    float mean = ql[lb][j], ls = ql[lb][j+32];
    z0[(b0+lb)*Z_ + j] = mean + __expf(ls)*eps[(b0+lb)*Z_ + j];
    float pmj = pm[j], plsj = pls[j];
    float dm = mean - pmj;
    kl = plsj - ls + (__expf(2.f*ls) + dm*dm) / (2.f*__expf(2.f*plsj)) - 0.5f;
  }
  #pragma unroll
  for (int s2 = 32; s2 > 0; s2 >>= 1) kl += __shfl_down(kl, s2, 64);
  if (j == 0) atomicAdd(out + 1, kl * (1.f/1024.f));
}

// ---------------------------------------------------------------------------
// SDE round-8: r6 MFMA structure + two latency fixes:
//  (a) diff GEMM moved to the B1->B2 slot on waves 2,3 (gh ready after B1;
//      result passed via diffL[16][36] f32, padded = conflict-free).
//      GEMM2's 8 h2 tiles re-split 3/3/1/1 so the phase is balanced
//      (waves 0,1: 15 MFMA; waves 2,3: diff 5 + h2 5 = 10). Phase 3 is now
//      a single 5-MFMA drift chain + one 16B LDS read.
//  (b) dW / xs(ev) prefetched one FULL step ahead (register double-buffer);
//      previously issued and consumed in the same step, exposing ~300cy of
//      HBM latency at phase 3.
// ---------------------------------------------------------------------------
__global__ __launch_bounds__(256, 1) void sde_mfma_kernel(
    const float* __restrict__ z0, const float* __restrict__ ts,
    const float* __restrict__ dW, const float* __restrict__ xs,
    const float* __restrict__ fW1, const float* __restrict__ fb1,
    const float* __restrict__ fW2, const float* __restrict__ fb2,
    const float* __restrict__ fW3, const float* __restrict__ fb3,
    const float* __restrict__ gW1, const float* __restrict__ gb1,
    const float* __restrict__ gW2, const float* __restrict__ gb2,
    const float* __restrict__ pW, const float* __restrict__ pb,
    float* __restrict__ out)
{
  __shared__ f16 Xa[16*72];       // [batch][72]: 0..31 z, 32 t, 33 one, 34 t-resid
  __shared__ f16 h1A[16*168];     // [batch][168]: 0..127 h1, 128 one, rest 0
  __shared__ f16 ghA[16*168];
  __shared__ f16 h2A[16*168];
  __shared__ float diffL[16][36]; // [batch][z + pad4] diffusion pass-through
  __shared__ float tsL[516];
  __shared__ float lred[4];

  const int t    = threadIdx.x;
  const int wid  = t >> 6;
  const int lane = t & 63;
  const int lr = lane & 15;       // tile-row (A) / batch-col (B/C)
  const int lg = lane >> 4;       // k-group / C row-group
  const int r0 = blockIdx.x * 16;

  // ---- stage W1pad (K=64): 4 tiles/wave -> 8 frags
  v8h w1r[8];
  #pragma unroll
  for (int nl = 0; nl < 4; ++nl) {
    const int n = wid*4 + nl;
    const float* src = (n < 8) ? (fW1 + (n*16+lr)*33) : (gW1 + ((n-8)*16+lr)*33);
    const float bsv  = (n < 8) ? fb1[n*16+lr] : gb1[(n-8)*16+lr];
    #pragma unroll
    for (int ks = 0; ks < 2; ++ks) {
      v8h w;
      #pragma unroll
      for (int j = 0; j < 8; ++j) {
        const int kp = ks*32 + lg*8 + j;
        float v;
        if (kp < 32)                   v = src[1+kp];
        else if (kp == 32 || kp == 34) v = src[0];
        else if (kp == 33)             v = bsv;
        else                           v = 0.f;
        w[j] = (f16)v;
      }
      w1r[nl*2+ks] = w;
    }
  }
  // ---- stage W2pad (K=160): tiles split 3/3/1/1 across waves
  const int nt2 = (wid < 2) ? 3 : 1;
  const int tb2 = (wid < 2) ? wid*3 : 6 + (wid - 2);
  v8h w2r[15];
  #pragma unroll
  for (int nl = 0; nl < 3; ++nl) {
    if (nl < nt2) {
      const int n = tb2 + nl;
      const float* src = fW2 + (n*16+lr)*128;
      const float bsv = fb2[n*16+lr];
      #pragma unroll
      for (int ks = 0; ks < 5; ++ks) {
        v8h w;
        #pragma unroll
        for (int j = 0; j < 8; ++j) {
          const int kp = ks*32 + lg*8 + j;
          float v = (kp < 128) ? src[kp] : ((kp == 128) ? bsv : 0.f);
          w[j] = (f16)v;
        }
        w2r[nl*5+ks] = w;
      }
    }
  }
  // ---- waves 0,1: drift weights (fW3, z-half wid); waves 2,3: diff (gW2)
  v8h w3[5];
  {
    const int zh = (wid < 2) ? wid : (wid - 2);
    const float* s3 = (wid < 2) ? (fW3 + (zh*16+lr)*128) : (gW2 + (zh*16+lr)*128);
    const float b3 = (wid < 2) ? fb3[zh*16+lr] : gb2[zh*16+lr];
    #pragma unroll
    for (int ks = 0; ks < 5; ++ks) {
      v8h w;
      #pragma unroll
      for (int j = 0; j < 8; ++j) {
        const int kp = ks*32 + lg*8 + j;
        w[j] = (f16)((kp < 128) ? s3[kp] : ((kp == 128) ? b3 : 0.f));
      }
      w3[ks] = w;
    }
  }
  // ---- stage pWpad (K=64): 1 tile/wave -> 2 frags
  v8h pwr[2];
  {
    const float* sp = pW + (wid*16+lr)*32;
    const float bp = pb[wid*16+lr];
    #pragma unroll
    for (int ks = 0; ks < 2; ++ks) {
      v8h w;
      #pragma unroll
      for (int j = 0; j < 8; ++j) {
        const int kp = ks*32 + lg*8 + j;
        w[j] = (f16)((kp < 32) ? sp[kp] : ((kp == 33) ? bp : 0.f));
      }
      pwr[ks] = w;
    }
  }

  // ---- init LDS
  for (int i = t; i < 16*72; i += 256) Xa[i] = (f16)0.f;
  for (int i = t; i < 16*168; i += 256) {
    h1A[i] = (f16)0.f; ghA[i] = (f16)0.f; h2A[i] = (f16)0.f;
  }
  for (int i = t; i < 515; i += 256) tsL[i] = ts[i];
  __syncthreads();
  if (t < 16) {
    Xa[t*72 + 33] = (f16)1.f;
    h1A[t*168 + 128] = (f16)1.f;
    ghA[t*168 + 128] = (f16)1.f;
    h2A[t*168 + 128] = (f16)1.f;
    const float t0 = tsL[0];
    const f16 th = (f16)t0;
    Xa[t*72 + 32] = th;
    Xa[t*72 + 34] = (f16)(t0 - (float)th);
  }
  const v4f zero4 = {0.f, 0.f, 0.f, 0.f};
  v4f zm = zero4;                 // waves 0,1: z-half wid, batch lr, dims lg*4+i
  if (wid < 2) {
    zm = *(const v4f*)&z0[(r0+lr)*Z_ + wid*16 + lg*4];
    v4h a;
    #pragma unroll
    for (int i = 0; i < 4; ++i) a[i] = (f16)zm[i];
    *(v4h*)&Xa[lr*72 + wid*16 + lg*4] = a;
  }
  float loss = 0.f;
  // prologue: step-0 dW (xs not needed at step 0: ln=1 is neither ev nor od)
  v4f dwv = zero4, xv = zero4;
  if (wid < 2) dwv = *(const v4f*)&dW[(0*B_ + r0 + lr)*Z_ + wid*16 + lg*4];
  __syncthreads();

  #pragma unroll 1
  for (int l = 0; l < NSTEP; ++l) {
    const float dt  = tsL[l+1] - tsL[l];
    const float sdt = sqrtf(dt);
    const int ln = l + 1;
    const bool ev = ((ln & 1) == 0) && ln >= 2 && ln <= 512;
    const bool od = ((ln & 1) == 1) && ln >= 3 && ln <= 511;

    // issue NEXT-step global loads (consumed next iteration)
    v4f dwN = zero4, xvN = zero4;
    if (wid < 2 && l + 1 < NSTEP)
      dwN = *(const v4f*)&dW[((l+1)*B_ + r0 + lr)*Z_ + wid*16 + lg*4];
    {
      const int ln2 = l + 2;
      if (((ln2 & 1) == 0) && ln2 >= 2 && ln2 <= 512)
        xvN = *(const v4f*)&xs[(((ln2-2)>>1)*B_ + r0 + lr)*D_ + wid*16 + lg*4];
    }

    // ---- GEMM1: [h1; gh]^T = W1pad @ X^T   (4 tiles/wave x 2 k-steps)
    {
      const v8h bx0 = *(const v8h*)&Xa[lr*72 +  0 + lg*8];
      const v8h bx1 = *(const v8h*)&Xa[lr*72 + 32 + lg*8];
      #pragma unroll
      for (int nl = 0; nl < 4; ++nl) {
        v4f acc = __builtin_amdgcn_mfma_f32_16x16x32_f16(w1r[nl*2+0], bx0, zero4, 0, 0, 0);
        acc = __builtin_amdgcn_mfma_f32_16x16x32_f16(w1r[nl*2+1], bx1, acc, 0, 0, 0);
        v4h o;
        #pragma unroll
        for (int i = 0; i < 4; ++i) o[i] = (f16)fmaxf(acc[i], 0.f);
        if (wid < 2) *(v4h*)&h1A[lr*168 + (wid*4+nl)*16 + lg*4] = o;
        else         *(v4h*)&ghA[lr*168 + ((wid-2)*4+nl)*16 + lg*4] = o;
      }
    }
    __syncthreads();   // B1

    // ---- B1->B2 slot: waves 2,3 compute diff (gh ready) then 1 h2 tile;
    //      waves 0,1 compute 3 h2 tiles each.
    {
      if (wid >= 2) {
        v4f fac = zero4;
        #pragma unroll
        for (int ks = 0; ks < 5; ++ks) {
          const v8h bgf = *(const v8h*)&ghA[lr*168 + ks*32 + lg*8];
          fac = __builtin_amdgcn_mfma_f32_16x16x32_f16(w3[ks], bgf, fac, 0, 0, 0);
        }
        *(v4f*)&diffL[lr][(wid-2)*16 + lg*4] = fac;
      }
      v8h bh[5];
      #pragma unroll
      for (int ks = 0; ks < 5; ++ks) bh[ks] = *(const v8h*)&h1A[lr*168 + ks*32 + lg*8];
      #pragma unroll
      for (int nl = 0; nl < 3; ++nl) {
        if (nl < nt2) {
          v4f acc = zero4;
          #pragma unroll
          for (int ks = 0; ks < 5; ++ks)
            acc = __builtin_amdgcn_mfma_f32_16x16x32_f16(w2r[nl*5+ks], bh[ks], acc, 0, 0, 0);
          v4h o;
          #pragma unroll
          for (int i = 0; i < 4; ++i) o[i] = (f16)fmaxf(acc[i], 0.f);
          *(v4h*)&h2A[lr*168 + (tb2+nl)*16 + lg*4] = o;
        }
      }
    }
    __syncthreads();   // B2

    // ---- phase 3: waves 0,1 drift (5-chain) + diffL read + z update;
    //      wave 3 writes next-step t-columns
    if (wid < 2) {
      v4f dac = zero4;
      #pragma unroll
      for (int ks = 0; ks < 5; ++ks) {
        const v8h b2f = *(const v8h*)&h2A[lr*168 + ks*32 + lg*8];
        dac = __builtin_amdgcn_mfma_f32_16x16x32_f16(w3[ks], b2f, dac, 0, 0, 0);
      }
      const v4f dv = *(const v4f*)&diffL[lr][wid*16 + lg*4];
      #pragma unroll
      for (int i = 0; i < 4; ++i) zm[i] += dac[i]*dt + dv[i]*(sdt*dwv[i]);
      v4h a;
      #pragma unroll
      for (int i = 0; i < 4; ++i) a[i] = (f16)zm[i];
      *(v4h*)&Xa[lr*72 + wid*16 + lg*4] = a;
    } else if (wid == 3 && lg == 0) {
      const float tn = tsL[l+1];
      const f16 th = (f16)tn;
      Xa[lr*72 + 32] = th;
      Xa[lr*72 + 34] = (f16)(tn - (float)th);
    }
    __syncthreads();   // B3

    // ---- proj (1 tile/wave), barrier-free tail (Xa stable until next B2)
    if (ev || od) {
      const v8h px0 = *(const v8h*)&Xa[lr*72 +  0 + lg*8];
      const v8h px1 = *(const v8h*)&Xa[lr*72 + 32 + lg*8];
      v4f a = __builtin_amdgcn_mfma_f32_16x16x32_f16(pwr[0], px0, zero4, 0, 0, 0);
      v4f p = __builtin_amdgcn_mfma_f32_16x16x32_f16(pwr[1], px1, a, 0, 0, 0);
      if (ev) {
        #pragma unroll
        for (int i = 0; i < 4; ++i) { float d = p[i] - xv[i]; loss = fmaf(d, d, loss); }
      } else {
        float* op = out + 2 + (((ln-3)>>1)*B_ + r0 + lr)*D_ + wid*16 + lg*4;
        *(f2*)&op[0] = (f2){p[0], p[1]};
        *(f2*)&op[2] = (f2){p[2], p[3]};
      }
    }
    dwv = dwN; xv = xvN;
  }

  #pragma unroll
  for (int s2 = 32; s2 > 0; s2 >>= 1) loss += __shfl_down(loss, s2, 64);
  if (lane == 0) lred[wid] = loss;
  __syncthreads();
  if (t == 0)
    atomicAdd(out + 0, (lred[0] + lred[1] + lred[2] + lred[3]) * (1.f/16777216.f));
}

extern "C" void kernel_launch(void* const* d_in, const int* in_sizes, int n_in,
                              void* d_out, int out_size, void* d_ws, size_t ws_size,
                              hipStream_t stream) {
  (void)in_sizes; (void)n_in; (void)out_size; (void)ws_size;
  const float* xs   = (const float*)d_in[0];
  const float* ts   = (const float*)d_in[1];
  const float* eps  = (const float*)d_in[2];
  const float* dWp  = (const float*)d_in[3];
  const float* Wih  = (const float*)d_in[4];
  const float* Whh  = (const float*)d_in[5];
  const float* bih  = (const float*)d_in[6];
  const float* bhh  = (const float*)d_in[7];
  const float* encW = (const float*)d_in[8];
  const float* encB = (const float*)d_in[9];
  const float* qW   = (const float*)d_in[10];
  const float* qB   = (const float*)d_in[11];
  const float* fW1  = (const float*)d_in[12];
  const float* fb1  = (const float*)d_in[13];
  const float* fW2  = (const float*)d_in[14];
  const float* fb2  = (const float*)d_in[15];
  const float* fW3  = (const float*)d_in[16];
  const float* fb3  = (const float*)d_in[17];
  const float* gW1  = (const float*)d_in[18];
  const float* gb1  = (const float*)d_in[19];
  const float* gW2  = (const float*)d_in[20];
  const float* gb2  = (const float*)d_in[21];
  const float* pW   = (const float*)d_in[22];
  const float* pb   = (const float*)d_in[23];
  const float* pm   = (const float*)d_in[24];
  const float* pls  = (const float*)d_in[25];

  float* out = (float*)d_out;
  float* ws  = (float*)d_ws;
  float* hT = ws;              // 1024*128 floats
  float* z0 = ws + 131072;     // 1024*32 floats

  hipMemsetAsync(d_out, 0, 2*sizeof(float), stream);
  hipLaunchKernelGGL(gru_mfma_kernel, dim3(64), dim3(512), 0, stream,
                     xs, Wih, Whh, bih, bhh, hT);
  hipLaunchKernelGGL(enc_kernel, dim3(256), dim3(256), 0, stream,
                     hT, encW, encB, qW, qB, eps, pm, pls, z0, out);
  hipLaunchKernelGGL(sde_mfma_kernel, dim3(64), dim3(256), 0, stream,
                     z0, ts, dWp, xs, fW1, fb1, fW2, fb2, fW3, fb3,
                     gW1, gb1, gW2, gb2, pW, pb, out);
}

// Round 9
// 1273.733 us; speedup vs baseline: 1.0401x; 1.0401x over previous
//
#include <hip/hip_runtime.h>

typedef _Float16 f16;
typedef _Float16 h2 __attribute__((ext_vector_type(2)));
typedef _Float16 h8 __attribute__((ext_vector_type(8)));
typedef _Float16 v8h __attribute__((ext_vector_type(8)));
typedef _Float16 v4h __attribute__((ext_vector_type(4)));
typedef float    f4 __attribute__((ext_vector_type(4)));
typedef float    v4f __attribute__((ext_vector_type(4)));
typedef float    f2 __attribute__((ext_vector_type(2)));

#define S_  256
#define B_  1024
#define D_  64
#define H_  128
#define Z_  32
#define BD_ (B_*D_)
#define NSTEP 514

// Counted-wait barrier (T3/T4, HK pattern): order LDS producer->consumer
// (lgkmcnt(0)) but leave GLOBAL loads in flight (no vmcnt drain). The
// compiler-emitted s_waitcnt vmcnt(N) lands at the actual consume point.
// __syncthreads() would drain vmcnt(0) at every barrier -> ~500-900cy HBM
// latency exposed per step (the r6/r7 hidden stall).
#define BAR() do { \
  asm volatile("s_waitcnt lgkmcnt(0)" ::: "memory"); \
  __builtin_amdgcn_s_barrier(); \
} while (0)

__device__ __forceinline__ h8 ld8(const float* p) {   // 32B-aligned src
  f4 a = *(const f4*)p;
  f4 b = *(const f4*)(p + 4);
  h8 w;
  w[0]=(f16)a[0]; w[1]=(f16)a[1]; w[2]=(f16)a[2]; w[3]=(f16)a[3];
  w[4]=(f16)b[0]; w[5]=(f16)b[1]; w[6]=(f16)b[2]; w[7]=(f16)b[3];
  return w;
}

__device__ __forceinline__ float sigm(float x) { return 1.f / (1.f + __expf(-x)); }
__device__ __forceinline__ float tanh_(float x) {
  float e = __expf(-2.f * fabsf(x));
  float t = (1.f - e) / (1.f + e);
  return copysignf(t, x);
}

// ---------------------------------------------------------------------------
// GRU: r7 4-wave MFMA structure (measured ~620us) with the in-loop
// __syncthreads replaced by BAR() — xs prefetch loads now stay in flight
// across the barrier (vmcnt wait lands at next-step consume, ~full-step
// cover) instead of draining every step.
// ---------------------------------------------------------------------------
__global__ __launch_bounds__(256, 1) void gru_mfma_kernel(
    const float* __restrict__ xs, const float* __restrict__ Wih,
    const float* __restrict__ Whh, const float* __restrict__ bih,
    const float* __restrict__ bhh, float* __restrict__ hT)
{
  __shared__ f16 hB[2][16][136];   // [buf][batch][h + pad8]

  const int t    = threadIdx.x;
  const int wid  = t >> 6;
  const int lane = t & 63;
  const int lr = lane & 15;        // A row / batch col
  const int lg = lane >> 4;        // k-group / C row-group
  const int r0 = blockIdx.x * 16;

  // ---- weight A-frags: row = lr, k = ks*32 + lg*8 + j
  v8h whhR[2][4], whhZ[2][4], whhN[2][4];
  v8h wihR[2][2], wihZ[2][2], wihN[2][2];
  #pragma unroll
  for (int tt = 0; tt < 2; ++tt) {
    const int nr = wid*32 + tt*16 + lr;
    #pragma unroll
    for (int ks = 0; ks < 4; ++ks) {
      whhR[tt][ks] = ld8(Whh + (      nr)*H_ + ks*32 + lg*8);
      whhZ[tt][ks] = ld8(Whh + (128 + nr)*H_ + ks*32 + lg*8);
      whhN[tt][ks] = ld8(Whh + (256 + nr)*H_ + ks*32 + lg*8);
    }
    #pragma unroll
    for (int ks = 0; ks < 2; ++ks) {
      wihR[tt][ks] = ld8(Wih + (      nr)*D_ + ks*32 + lg*8);
      wihZ[tt][ks] = ld8(Wih + (128 + nr)*D_ + ks*32 + lg*8);
      wihN[tt][ks] = ld8(Wih + (256 + nr)*D_ + ks*32 + lg*8);
    }
  }
  // ---- per-lane gate bias consts (neurons wid*32 + tt*16 + lg*4 + i)
  v4f birh[2], bizh[2], binv[2], bhnv[2];
  #pragma unroll
  for (int tt = 0; tt < 2; ++tt) {
    const int nb = wid*32 + tt*16 + lg*4;
    v4f a = *(const v4f*)&bih[nb],     b = *(const v4f*)&bhh[nb];
    v4f c = *(const v4f*)&bih[128+nb], d = *(const v4f*)&bhh[128+nb];
    birh[tt] = a + b;
    bizh[tt] = c + d;
    binv[tt] = *(const v4f*)&bih[256+nb];
    bhnv[tt] = *(const v4f*)&bhh[256+nb];
  }

  for (int i = t; i < 16*136; i += 256) ((f16*)hB[0])[i] = (f16)0.f;
  v4f hm[2] = { {0.f,0.f,0.f,0.f}, {0.f,0.f,0.f,0.f} };  // fp32 h masters
  const v4f zero4 = {0.f, 0.f, 0.f, 0.f};

  // x B-frags for step 0 (x_rev[0] = xs[S-1])
  v8h bx0 = ld8(xs + (S_-1)*BD_ + (r0+lr)*D_ + lg*8);
  v8h bx1 = ld8(xs + (S_-1)*BD_ + (r0+lr)*D_ + 32 + lg*8);
  __syncthreads();

  int p = 0;
  #pragma unroll 1
  for (int s = 0; s < S_; ++s) {
    v8h nx0 = bx0, nx1 = bx1;
    if (s < S_-1) {
      const float* xp = xs + (S_-2-s)*BD_ + (r0+lr)*D_;
      nx0 = ld8(xp + lg*8);
      nx1 = ld8(xp + 32 + lg*8);
    }
    v8h bh[4];
    #pragma unroll
    for (int ks = 0; ks < 4; ++ks)
      bh[ks] = *(const v8h*)&hB[p][lr][ks*32 + lg*8];

    #pragma unroll
    for (int tt = 0; tt < 2; ++tt) {
      v4f ar  = __builtin_amdgcn_mfma_f32_16x16x32_f16(wihR[tt][0], bx0, zero4, 0,0,0);
      v4f az  = __builtin_amdgcn_mfma_f32_16x16x32_f16(wihZ[tt][0], bx0, zero4, 0,0,0);
      v4f anx = __builtin_amdgcn_mfma_f32_16x16x32_f16(wihN[tt][0], bx0, zero4, 0,0,0);
      ar  = __builtin_amdgcn_mfma_f32_16x16x32_f16(wihR[tt][1], bx1, ar,  0,0,0);
      az  = __builtin_amdgcn_mfma_f32_16x16x32_f16(wihZ[tt][1], bx1, az,  0,0,0);
      anx = __builtin_amdgcn_mfma_f32_16x16x32_f16(wihN[tt][1], bx1, anx, 0,0,0);
      v4f anh = zero4;
      #pragma unroll
      for (int ks = 0; ks < 4; ++ks) {
        ar  = __builtin_amdgcn_mfma_f32_16x16x32_f16(whhR[tt][ks], bh[ks], ar,  0,0,0);
        az  = __builtin_amdgcn_mfma_f32_16x16x32_f16(whhZ[tt][ks], bh[ks], az,  0,0,0);
        anh = __builtin_amdgcn_mfma_f32_16x16x32_f16(whhN[tt][ks], bh[ks], anh, 0,0,0);
      }
      v4h o;
      #pragma unroll
      for (int i = 0; i < 4; ++i) {
        float r  = sigm(ar[i] + birh[tt][i]);
        float zg = sigm(az[i] + bizh[tt][i]);
        float n  = tanh_(anx[i] + binv[tt][i] + r*(anh[i] + bhnv[tt][i]));
        hm[tt][i] = (1.f - zg)*n + zg*hm[tt][i];
        o[i] = (f16)hm[tt][i];
      }
      *(v4h*)&hB[p^1][lr][wid*32 + tt*16 + lg*4] = o;
    }
    BAR();
    p ^= 1;
    bx0 = nx0; bx1 = nx1;
  }

  #pragma unroll
  for (int tt = 0; tt < 2; ++tt)
    *(v4f*)&hT[(r0+lr)*H_ + wid*32 + tt*16 + lg*4] = hm[tt];
}

// ---------------------------------------------------------------------------
// Encoder head (unchanged; tiny): 256 blocks x 4 rows.
// ---------------------------------------------------------------------------
__global__ __launch_bounds__(256) void enc_kernel(
    const float* __restrict__ hT, const float* __restrict__ encW,
    const float* __restrict__ encB, const float* __restrict__ qW,
    const float* __restrict__ qB, const float* __restrict__ eps,
    const float* __restrict__ pm, const float* __restrict__ pls,
    float* __restrict__ z0, float* __restrict__ out)
{
  __shared__ float hTl[4][128];
  __shared__ float ctx[4][64];
  __shared__ float ql[4][64];
  const int t = threadIdx.x;
  const int b0 = blockIdx.x * 4;
  const int lb = t >> 6, j = t & 63;

  for (int i = t; i < 512; i += 256) hTl[i>>7][i&127] = hT[b0*H_ + i];
  __syncthreads();

  float acc = encB[j];
  #pragma unroll
  for (int k = 0; k < 128; k += 4) {
    f4 w = *(const f4*)&encW[j*128 + k];
    acc += hTl[lb][k]*w[0] + hTl[lb][k+1]*w[1] + hTl[lb][k+2]*w[2] + hTl[lb][k+3]*w[3];
  }
  ctx[lb][j] = acc;
  __syncthreads();

  float q = qB[j];
  #pragma unroll
  for (int k = 0; k < 64; k += 4) {
    f4 w = *(const f4*)&qW[j*64 + k];
    q += ctx[lb][k]*w[0] + ctx[lb][k+1]*w[1] + ctx[lb][k+2]*w[2] + ctx[lb][k+3]*w[3];
  }
  ql[lb][j] = q;
  __syncthreads();

  float kl = 0.f;
  if (j < 32) {
    float mean = ql[lb][j], ls = ql[lb][j+32];
    z0[(b0+lb)*Z_ + j] = mean + __expf(ls)*eps[(b0+lb)*Z_ + j];
    float pmj = pm[j], plsj = pls[j];
    float dm = mean - pmj;
    kl = plsj - ls + (__expf(2.f*ls) + dm*dm) / (2.f*__expf(2.f*plsj)) - 0.5f;
  }
  #pragma unroll
  for (int s2 = 32; s2 > 0; s2 >>= 1) kl += __shfl_down(kl, s2, 64);
  if (j == 0) atomicAdd(out + 1, kl * (1.f/1024.f));
}

// ---------------------------------------------------------------------------
// SDE: r6 MFMA structure verbatim (measured 589us; r8's rebalance reverted)
// with in-loop __syncthreads replaced by BAR() — dW/xs loads stay in flight
// across B1/B2 (vmcnt wait lands at phase3/proj consume, ~700-1000cy cover).
// ---------------------------------------------------------------------------
__global__ __launch_bounds__(256, 1) void sde_mfma_kernel(
    const float* __restrict__ z0, const float* __restrict__ ts,
    const float* __restrict__ dW, const float* __restrict__ xs,
    const float* __restrict__ fW1, const float* __restrict__ fb1,
    const float* __restrict__ fW2, const float* __restrict__ fb2,
    const float* __restrict__ fW3, const float* __restrict__ fb3,
    const float* __restrict__ gW1, const float* __restrict__ gb1,
    const float* __restrict__ gW2, const float* __restrict__ gb2,
    const float* __restrict__ pW, const float* __restrict__ pb,
    float* __restrict__ out)
{
  __shared__ f16 Xa[16*72];       // [batch][72]: 0..31 z, 32 t, 33 one, 34 t-resid
  __shared__ f16 h1A[16*168];     // [batch][168]: 0..127 h1, 128 one, rest 0
  __shared__ f16 ghA[16*168];
  __shared__ f16 h2A[16*168];
  __shared__ float tsL[516];
  __shared__ float lred[4];

  const int t    = threadIdx.x;
  const int wid  = t >> 6;
  const int lane = t & 63;
  const int lr = lane & 15;       // tile-row (A) / batch-col (B/C)
  const int lg = lane >> 4;       // k-group / C row-group
  const int r0 = blockIdx.x * 16;
  const int wz = wid & 1;         // z-half for phase3 roles

  // ---- stage W1pad (K=64): 4 tiles/wave -> 8 frags
  v8h w1r[8];
  #pragma unroll
  for (int nl = 0; nl < 4; ++nl) {
    const int n = wid*4 + nl;
    const float* src = (n < 8) ? (fW1 + (n*16+lr)*33) : (gW1 + ((n-8)*16+lr)*33);
    const float bsv  = (n < 8) ? fb1[n*16+lr] : gb1[(n-8)*16+lr];
    #pragma unroll
    for (int ks = 0; ks < 2; ++ks) {
      v8h w;
      #pragma unroll
      for (int j = 0; j < 8; ++j) {
        const int kp = ks*32 + lg*8 + j;
        float v;
        if (kp < 32)                   v = src[1+kp];
        else if (kp == 32 || kp == 34) v = src[0];
        else if (kp == 33)             v = bsv;
        else                           v = 0.f;
        w[j] = (f16)v;
      }
      w1r[nl*2+ks] = w;
    }
  }
  // ---- stage W2pad (K=160): 2 tiles/wave -> 10 frags
  v8h w2r[10];
  #pragma unroll
  for (int nl = 0; nl < 2; ++nl) {
    const int n = wid*2 + nl;
    const float* src = fW2 + (n*16+lr)*128;
    const float bsv = fb2[n*16+lr];
    #pragma unroll
    for (int ks = 0; ks < 5; ++ks) {
      v8h w;
      #pragma unroll
      for (int j = 0; j < 8; ++j) {
        const int kp = ks*32 + lg*8 + j;
        float v = (kp < 128) ? src[kp] : ((kp == 128) ? bsv : 0.f);
        w[j] = (f16)v;
      }
      w2r[nl*5+ks] = w;
    }
  }
  // ---- stage W3 (drift fW3 + diff gW2, K=160), z-half wz: 10 frags
  v8h w3d[5], w3g[5];
  {
    const float* sd = fW3 + (wz*16+lr)*128;
    const float* sg = gW2 + (wz*16+lr)*128;
    const float bd = fb3[wz*16+lr], bg = gb2[wz*16+lr];
    #pragma unroll
    for (int ks = 0; ks < 5; ++ks) {
      v8h wd, wg;
      #pragma unroll
      for (int j = 0; j < 8; ++j) {
        const int kp = ks*32 + lg*8 + j;
        wd[j] = (f16)((kp < 128) ? sd[kp] : ((kp == 128) ? bd : 0.f));
        wg[j] = (f16)((kp < 128) ? sg[kp] : ((kp == 128) ? bg : 0.f));
      }
      w3d[ks] = wd; w3g[ks] = wg;
    }
  }
  // ---- stage pWpad (K=64): 1 tile/wave -> 2 frags
  v8h pwr[2];
  {
    const float* sp = pW + (wid*16+lr)*32;
    const float bp = pb[wid*16+lr];
    #pragma unroll
    for (int ks = 0; ks < 2; ++ks) {
      v8h w;
      #pragma unroll
      for (int j = 0; j < 8; ++j) {
        const int kp = ks*32 + lg*8 + j;
        w[j] = (f16)((kp < 32) ? sp[kp] : ((kp == 33) ? bp : 0.f));
      }
      pwr[ks] = w;
    }
  }

  // ---- init LDS
  for (int i = t; i < 16*72; i += 256) Xa[i] = (f16)0.f;
  for (int i = t; i < 16*168; i += 256) {
    h1A[i] = (f16)0.f; ghA[i] = (f16)0.f; h2A[i] = (f16)0.f;
  }
  for (int i = t; i < 515; i += 256) tsL[i] = ts[i];
  __syncthreads();
  if (t < 16) {
    Xa[t*72 + 33] = (f16)1.f;
    h1A[t*168 + 128] = (f16)1.f;
    ghA[t*168 + 128] = (f16)1.f;
    h2A[t*168 + 128] = (f16)1.f;
    const float t0 = tsL[0];
    const f16 th = (f16)t0;
    Xa[t*72 + 32] = th;
    Xa[t*72 + 34] = (f16)(t0 - (float)th);
  }
  const v4f zero4 = {0.f, 0.f, 0.f, 0.f};
  v4f zm = zero4;                 // waves 0,1: z-half wid, batch lr, dims lg*4+i
  if (wid < 2) {
    zm = *(const v4f*)&z0[(r0+lr)*Z_ + wid*16 + lg*4];
    v4h a;
    #pragma unroll
    for (int i = 0; i < 4; ++i) a[i] = (f16)zm[i];
    *(v4h*)&Xa[lr*72 + wid*16 + lg*4] = a;
  }
  float loss = 0.f;
  __syncthreads();

  #pragma unroll 1
  for (int l = 0; l < NSTEP; ++l) {
    const float dt  = tsL[l+1] - tsL[l];
    const float sdt = sqrtf(dt);
    const int ln = l + 1;
    const bool ev = ((ln & 1) == 0) && ln >= 2 && ln <= 512;
    const bool od = ((ln & 1) == 1) && ln >= 3 && ln <= 511;

    // global loads for this step (consumed at phase3/proj; with BAR() they
    // stay in flight across B1/B2 -> latency fully covered)
    v4f dwv = zero4;
    if (wid < 2) dwv = *(const v4f*)&dW[(l*B_ + r0 + lr)*Z_ + wid*16 + lg*4];
    v4f xv = zero4;
    if (ev) xv = *(const v4f*)&xs[(((ln-2)>>1)*B_ + r0 + lr)*D_ + wid*16 + lg*4];

    // ---- GEMM1: [h1; gh]^T = W1pad @ X^T   (4 tiles/wave x 2 k-steps)
    {
      const v8h bx0 = *(const v8h*)&Xa[lr*72 +  0 + lg*8];
      const v8h bx1 = *(const v8h*)&Xa[lr*72 + 32 + lg*8];
      #pragma unroll
      for (int nl = 0; nl < 4; ++nl) {
        v4f acc = __builtin_amdgcn_mfma_f32_16x16x32_f16(w1r[nl*2+0], bx0, zero4, 0, 0, 0);
        acc = __builtin_amdgcn_mfma_f32_16x16x32_f16(w1r[nl*2+1], bx1, acc, 0, 0, 0);
        v4h o;
        #pragma unroll
        for (int i = 0; i < 4; ++i) o[i] = (f16)fmaxf(acc[i], 0.f);
        if (wid < 2) *(v4h*)&h1A[lr*168 + (wid*4+nl)*16 + lg*4] = o;
        else         *(v4h*)&ghA[lr*168 + ((wid-2)*4+nl)*16 + lg*4] = o;
      }
    }
    BAR();   // B1

    // ---- GEMM2: h2^T = W2pad @ h1pad^T   (2 tiles/wave x 5 k-steps)
    {
      v8h bh[5];
      #pragma unroll
      for (int ks = 0; ks < 5; ++ks) bh[ks] = *(const v8h*)&h1A[lr*168 + ks*32 + lg*8];
      #pragma unroll
      for (int nl = 0; nl < 2; ++nl) {
        v4f acc = zero4;
        #pragma unroll
        for (int ks = 0; ks < 5; ++ks)
          acc = __builtin_amdgcn_mfma_f32_16x16x32_f16(w2r[nl*5+ks], bh[ks], acc, 0, 0, 0);
        v4h o;
        #pragma unroll
        for (int i = 0; i < 4; ++i) o[i] = (f16)fmaxf(acc[i], 0.f);
        *(v4h*)&h2A[lr*168 + (wid*2+nl)*16 + lg*4] = o;
      }
    }
    BAR();   // B2

    // ---- phase 3: waves 0,1 do drift+diff for z-half wid; wave 3 writes
    //      next step's t-columns
    if (wid < 2) {
      v4f dac = zero4, fac = zero4;
      #pragma unroll
      for (int ks = 0; ks < 5; ++ks) {
        const v8h b2f = *(const v8h*)&h2A[lr*168 + ks*32 + lg*8];
        const v8h bgf = *(const v8h*)&ghA[lr*168 + ks*32 + lg*8];
        dac = __builtin_amdgcn_mfma_f32_16x16x32_f16(w3d[ks], b2f, dac, 0, 0, 0);
        fac = __builtin_amdgcn_mfma_f32_16x16x32_f16(w3g[ks], bgf, fac, 0, 0, 0);
      }
      #pragma unroll
      for (int i = 0; i < 4; ++i) zm[i] += dac[i]*dt + fac[i]*(sdt*dwv[i]);
      v4h a;
      #pragma unroll
      for (int i = 0; i < 4; ++i) a[i] = (f16)zm[i];
      *(v4h*)&Xa[lr*72 + wid*16 + lg*4] = a;
    } else if (wid == 3 && lg == 0) {
      const float tn = tsL[l+1];
      const f16 th = (f16)tn;
      Xa[lr*72 + 32] = th;
      Xa[lr*72 + 34] = (f16)(tn - (float)th);
    }
    BAR();   // B3

    // ---- proj (1 tile/wave), barrier-free tail (Xa stable until next B2)
    if (ev || od) {
      const v8h px0 = *(const v8h*)&Xa[lr*72 +  0 + lg*8];
      const v8h px1 = *(const v8h*)&Xa[lr*72 + 32 + lg*8];
      v4f a = __builtin_amdgcn_mfma_f32_16x16x32_f16(pwr[0], px0, zero4, 0, 0, 0);
      v4f p = __builtin_amdgcn_mfma_f32_16x16x32_f16(pwr[1], px1, a, 0, 0, 0);
      if (ev) {
        #pragma unroll
        for (int i = 0; i < 4; ++i) { float d = p[i] - xv[i]; loss = fmaf(d, d, loss); }
      } else {
        float* op = out + 2 + (((ln-3)>>1)*B_ + r0 + lr)*D_ + wid*16 + lg*4;
        *(f2*)&op[0] = (f2){p[0], p[1]};
        *(f2*)&op[2] = (f2){p[2], p[3]};
      }
    }
  }

  #pragma unroll
  for (int s2 = 32; s2 > 0; s2 >>= 1) loss += __shfl_down(loss, s2, 64);
  if (lane == 0) lred[wid] = loss;
  __syncthreads();
  if (t == 0)
    atomicAdd(out + 0, (lred[0] + lred[1] + lred[2] + lred[3]) * (1.f/16777216.f));
}

extern "C" void kernel_launch(void* const* d_in, const int* in_sizes, int n_in,
                              void* d_out, int out_size, void* d_ws, size_t ws_size,
                              hipStream_t stream) {
  (void)in_sizes; (void)n_in; (void)out_size; (void)ws_size;
  const float* xs   = (const float*)d_in[0];
  const float* ts   = (const float*)d_in[1];
  const float* eps  = (const float*)d_in[2];
  const float* dWp  = (const float*)d_in[3];
  const float* Wih  = (const float*)d_in[4];
  const float* Whh  = (const float*)d_in[5];
  const float* bih  = (const float*)d_in[6];
  const float* bhh  = (const float*)d_in[7];
  const float* encW = (const float*)d_in[8];
  const float* encB = (const float*)d_in[9];
  const float* qW   = (const float*)d_in[10];
  const float* qB   = (const float*)d_in[11];
  const float* fW1  = (const float*)d_in[12];
  const float* fb1  = (const float*)d_in[13];
  const float* fW2  = (const float*)d_in[14];
  const float* fb2  = (const float*)d_in[15];
  const float* fW3  = (const float*)d_in[16];
  const float* fb3  = (const float*)d_in[17];
  const float* gW1  = (const float*)d_in[18];
  const float* gb1  = (const float*)d_in[19];
  const float* gW2  = (const float*)d_in[20];
  const float* gb2  = (const float*)d_in[21];
  const float* pW   = (const float*)d_in[22];
  const float* pb   = (const float*)d_in[23];
  const float* pm   = (const float*)d_in[24];
  const float* pls  = (const float*)d_in[25];

  float* out = (float*)d_out;
  float* ws  = (float*)d_ws;
  float* hT = ws;              // 1024*128 floats
  float* z0 = ws + 131072;     // 1024*32 floats

  hipMemsetAsync(d_out, 0, 2*sizeof(float), stream);
  hipLaunchKernelGGL(gru_mfma_kernel, dim3(64), dim3(256), 0, stream,
                     xs, Wih, Whh, bih, bhh, hT);
  hipLaunchKernelGGL(enc_kernel, dim3(256), dim3(256), 0, stream,
                     hT, encW, encB, qW, qB, eps, pm, pls, z0, out);
  hipLaunchKernelGGL(sde_mfma_kernel, dim3(64), dim3(256), 0, stream,
                     z0, ts, dWp, xs, fW1, fb1, fW2, fb2, fW3, fb3,
                     gW1, gb1, gW2, gb2, pW, pb, out);
}

// Round 10
// 1063.817 us; speedup vs baseline: 1.2454x; 1.1973x over previous
//
#include <hip/hip_runtime.h>

typedef _Float16 f16;
typedef _Float16 h2 __attribute__((ext_vector_type(2)));
typedef _Float16 h8 __attribute__((ext_vector_type(8)));
typedef _Float16 v8h __attribute__((ext_vector_type(8)));
typedef _Float16 v4h __attribute__((ext_vector_type(4)));
typedef float    f4 __attribute__((ext_vector_type(4)));
typedef float    v4f __attribute__((ext_vector_type(4)));
typedef float    f2 __attribute__((ext_vector_type(2)));

#define S_  256
#define B_  1024
#define D_  64
#define H_  128
#define Z_  32
#define BD_ (B_*D_)
#define NSTEP 514

// lgkm-only barrier (global loads stay in flight; harmless, kept from r9)
#define BAR() do { \
  asm volatile("s_waitcnt lgkmcnt(0)" ::: "memory"); \
  __builtin_amdgcn_s_barrier(); \
} while (0)

__device__ __forceinline__ h8 cvt8(f4 a, f4 b) {
  h8 w;
  w[0]=(f16)a[0]; w[1]=(f16)a[1]; w[2]=(f16)a[2]; w[3]=(f16)a[3];
  w[4]=(f16)b[0]; w[5]=(f16)b[1]; w[6]=(f16)b[2]; w[7]=(f16)b[3];
  return w;
}

__device__ __forceinline__ h8 ld8(const float* p) {   // 32B-aligned src
  f4 a = *(const f4*)p;
  f4 b = *(const f4*)(p + 4);
  return cvt8(a, b);
}

__device__ __forceinline__ float sigm(float x) { return 1.f / (1.f + __expf(-x)); }
__device__ __forceinline__ float tanh_(float x) {
  float e = __expf(-2.f * fabsf(x));
  float t = (1.f - e) / (1.f + e);
  return copysignf(t, x);
}

// ---------------------------------------------------------------------------
// GRU round-10: r7 4-wave MFMA structure + two latency fixes:
//  (a) xs loads kept as RAW f4 regs through the step; f32->f16 cvt happens
//      only at iteration END (first use of the regs -> the compiler-placed
//      s_waitcnt vmcnt lands ~a full step after issue, hiding ~900cy of
//      HBM latency that ld8's immediate cvt exposed every step).
//  (b) 6-deep wih->whh MFMA chains split into parallel 2-deep (x-part) +
//      4-deep (h-part) chains + final VALU add (dep-MFMA latency ~100cy).
// ---------------------------------------------------------------------------
__global__ __launch_bounds__(256, 1) void gru_mfma_kernel(
    const float* __restrict__ xs, const float* __restrict__ Wih,
    const float* __restrict__ Whh, const float* __restrict__ bih,
    const float* __restrict__ bhh, float* __restrict__ hT)
{
  __shared__ f16 hB[2][16][136];   // [buf][batch][h + pad8]

  const int t    = threadIdx.x;
  const int wid  = t >> 6;
  const int lane = t & 63;
  const int lr = lane & 15;        // A row / batch col
  const int lg = lane >> 4;        // k-group / C row-group
  const int r0 = blockIdx.x * 16;

  // ---- weight A-frags: row = lr, k = ks*32 + lg*8 + j
  v8h whhR[2][4], whhZ[2][4], whhN[2][4];
  v8h wihR[2][2], wihZ[2][2], wihN[2][2];
  #pragma unroll
  for (int tt = 0; tt < 2; ++tt) {
    const int nr = wid*32 + tt*16 + lr;
    #pragma unroll
    for (int ks = 0; ks < 4; ++ks) {
      whhR[tt][ks] = ld8(Whh + (      nr)*H_ + ks*32 + lg*8);
      whhZ[tt][ks] = ld8(Whh + (128 + nr)*H_ + ks*32 + lg*8);
      whhN[tt][ks] = ld8(Whh + (256 + nr)*H_ + ks*32 + lg*8);
    }
    #pragma unroll
    for (int ks = 0; ks < 2; ++ks) {
      wihR[tt][ks] = ld8(Wih + (      nr)*D_ + ks*32 + lg*8);
      wihZ[tt][ks] = ld8(Wih + (128 + nr)*D_ + ks*32 + lg*8);
      wihN[tt][ks] = ld8(Wih + (256 + nr)*D_ + ks*32 + lg*8);
    }
  }
  // ---- per-lane gate bias consts (neurons wid*32 + tt*16 + lg*4 + i)
  v4f birh[2], bizh[2], binv[2], bhnv[2];
  #pragma unroll
  for (int tt = 0; tt < 2; ++tt) {
    const int nb = wid*32 + tt*16 + lg*4;
    v4f a = *(const v4f*)&bih[nb],     b = *(const v4f*)&bhh[nb];
    v4f c = *(const v4f*)&bih[128+nb], d = *(const v4f*)&bhh[128+nb];
    birh[tt] = a + b;
    bizh[tt] = c + d;
    binv[tt] = *(const v4f*)&bih[256+nb];
    bhnv[tt] = *(const v4f*)&bhh[256+nb];
  }

  for (int i = t; i < 16*136; i += 256) ((f16*)hB[0])[i] = (f16)0.f;
  v4f hm[2] = { {0.f,0.f,0.f,0.f}, {0.f,0.f,0.f,0.f} };  // fp32 h masters
  const v4f zero4 = {0.f, 0.f, 0.f, 0.f};

  // x B-frags for step 0 (prologue: immediate cvt is fine once)
  v8h bx0 = ld8(xs + (S_-1)*BD_ + (r0+lr)*D_ + lg*8);
  v8h bx1 = ld8(xs + (S_-1)*BD_ + (r0+lr)*D_ + 32 + lg*8);
  __syncthreads();

  int p = 0;
  #pragma unroll 1
  for (int s = 0; s < S_; ++s) {
    // issue raw loads for next step (NO cvt here — cvt at iteration end)
    f4 ra0 = zero4, rb0 = zero4, ra1 = zero4, rb1 = zero4;
    const bool have = (s < S_-1);
    if (have) {
      const float* xp = xs + (S_-2-s)*BD_ + (r0+lr)*D_;
      ra0 = *(const f4*)(xp + lg*8);
      rb0 = *(const f4*)(xp + lg*8 + 4);
      ra1 = *(const f4*)(xp + 32 + lg*8);
      rb1 = *(const f4*)(xp + 32 + lg*8 + 4);
    }
    v8h bh[4];
    #pragma unroll
    for (int ks = 0; ks < 4; ++ks)
      bh[ks] = *(const v8h*)&hB[p][lr][ks*32 + lg*8];

    #pragma unroll
    for (int tt = 0; tt < 2; ++tt) {
      // x-part chains (2-deep) parallel to h-part chains (4-deep)
      v4f ri  = __builtin_amdgcn_mfma_f32_16x16x32_f16(wihR[tt][0], bx0, zero4, 0,0,0);
      v4f zi  = __builtin_amdgcn_mfma_f32_16x16x32_f16(wihZ[tt][0], bx0, zero4, 0,0,0);
      v4f anx = __builtin_amdgcn_mfma_f32_16x16x32_f16(wihN[tt][0], bx0, zero4, 0,0,0);
      ri  = __builtin_amdgcn_mfma_f32_16x16x32_f16(wihR[tt][1], bx1, ri,  0,0,0);
      zi  = __builtin_amdgcn_mfma_f32_16x16x32_f16(wihZ[tt][1], bx1, zi,  0,0,0);
      anx = __builtin_amdgcn_mfma_f32_16x16x32_f16(wihN[tt][1], bx1, anx, 0,0,0);
      v4f rh = zero4, zh = zero4, anh = zero4;
      #pragma unroll
      for (int ks = 0; ks < 4; ++ks) {
        rh  = __builtin_amdgcn_mfma_f32_16x16x32_f16(whhR[tt][ks], bh[ks], rh,  0,0,0);
        zh  = __builtin_amdgcn_mfma_f32_16x16x32_f16(whhZ[tt][ks], bh[ks], zh,  0,0,0);
        anh = __builtin_amdgcn_mfma_f32_16x16x32_f16(whhN[tt][ks], bh[ks], anh, 0,0,0);
      }
      v4h o;
      #pragma unroll
      for (int i = 0; i < 4; ++i) {
        float r  = sigm(ri[i] + rh[i] + birh[tt][i]);
        float zg = sigm(zi[i] + zh[i] + bizh[tt][i]);
        float n  = tanh_(anx[i] + binv[tt][i] + r*(anh[i] + bhnv[tt][i]));
        hm[tt][i] = (1.f - zg)*n + zg*hm[tt][i];
        o[i] = (f16)hm[tt][i];
      }
      *(v4h*)&hB[p^1][lr][wid*32 + tt*16 + lg*4] = o;
    }
    BAR();
    // cvt raw->f16 for next iter: first USE of the loads — the vmcnt wait
    // lands here, ~a full step after issue.
    if (have) { bx0 = cvt8(ra0, rb0); bx1 = cvt8(ra1, rb1); }
    p ^= 1;
  }

  #pragma unroll
  for (int tt = 0; tt < 2; ++tt)
    *(v4f*)&hT[(r0+lr)*H_ + wid*32 + tt*16 + lg*4] = hm[tt];
}

// ---------------------------------------------------------------------------
// Encoder head (unchanged; tiny): 256 blocks x 4 rows.
// ---------------------------------------------------------------------------
__global__ __launch_bounds__(256) void enc_kernel(
    const float* __restrict__ hT, const float* __restrict__ encW,
    const float* __restrict__ encB, const float* __restrict__ qW,
    const float* __restrict__ qB, const float* __restrict__ eps,
    const float* __restrict__ pm, const float* __restrict__ pls,
    float* __restrict__ z0, float* __restrict__ out)
{
  __shared__ float hTl[4][128];
  __shared__ float ctx[4][64];
  __shared__ float ql[4][64];
  const int t = threadIdx.x;
  const int b0 = blockIdx.x * 4;
  const int lb = t >> 6, j = t & 63;

  for (int i = t; i < 512; i += 256) hTl[i>>7][i&127] = hT[b0*H_ + i];
  __syncthreads();

  float acc = encB[j];
  #pragma unroll
  for (int k = 0; k < 128; k += 4) {
    f4 w = *(const f4*)&encW[j*128 + k];
    acc += hTl[lb][k]*w[0] + hTl[lb][k+1]*w[1] + hTl[lb][k+2]*w[2] + hTl[lb][k+3]*w[3];
  }
  ctx[lb][j] = acc;
  __syncthreads();

  float q = qB[j];
  #pragma unroll
  for (int k = 0; k < 64; k += 4) {
    f4 w = *(const f4*)&qW[j*64 + k];
    q += ctx[lb][k]*w[0] + ctx[lb][k+1]*w[1] + ctx[lb][k+2]*w[2] + ctx[lb][k+3]*w[3];
  }
  ql[lb][j] = q;
  __syncthreads();

  float kl = 0.f;
  if (j < 32) {
    float mean = ql[lb][j], ls = ql[lb][j+32];
    z0[(b0+lb)*Z_ + j] = mean + __expf(ls)*eps[(b0+lb)*Z_ + j];
    float pmj = pm[j], plsj = pls[j];
    float dm = mean - pmj;
    kl = plsj - ls + (__expf(2.f*ls) + dm*dm) / (2.f*__expf(2.f*plsj)) - 0.5f;
  }
  #pragma unroll
  for (int s2 = 32; s2 > 0; s2 >>= 1) kl += __shfl_down(kl, s2, 64);
  if (j == 0) atomicAdd(out + 1, kl * (1.f/1024.f));
}

// ---------------------------------------------------------------------------
// SDE round-10: r6 structure + critical-path surgery:
//  (a) proj(l) hoisted into iteration l+1's GEMM1 region — it reads the SAME
//      Xa (z_{l+1}) as GEMM1, reusing bx0/bx1 (its ds_reads deleted); its
//      loss/out consumption is deferred to after GEMM2's issue, filling
//      dep-stall slots. Removes the ~400cy proj chain from the B3->B1 path.
//  (b) GEMM2 / phase-3 K-chains split 5-deep -> parallel 3+2 + VALU add
//      (dep-MFMA latency ~100cy -> ~240cy saved per phase).
// ---------------------------------------------------------------------------
__global__ __launch_bounds__(256, 1) void sde_mfma_kernel(
    const float* __restrict__ z0, const float* __restrict__ ts,
    const float* __restrict__ dW, const float* __restrict__ xs,
    const float* __restrict__ fW1, const float* __restrict__ fb1,
    const float* __restrict__ fW2, const float* __restrict__ fb2,
    const float* __restrict__ fW3, const float* __restrict__ fb3,
    const float* __restrict__ gW1, const float* __restrict__ gb1,
    const float* __restrict__ gW2, const float* __restrict__ gb2,
    const float* __restrict__ pW, const float* __restrict__ pb,
    float* __restrict__ out)
{
  __shared__ f16 Xa[16*72];       // [batch][72]: 0..31 z, 32 t, 33 one, 34 t-resid
  __shared__ f16 h1A[16*168];     // [batch][168]: 0..127 h1, 128 one, rest 0
  __shared__ f16 ghA[16*168];
  __shared__ f16 h2A[16*168];
  __shared__ float tsL[516];
  __shared__ float lred[4];

  const int t    = threadIdx.x;
  const int wid  = t >> 6;
  const int lane = t & 63;
  const int lr = lane & 15;       // tile-row (A) / batch-col (B/C)
  const int lg = lane >> 4;       // k-group / C row-group
  const int r0 = blockIdx.x * 16;
  const int wz = wid & 1;         // z-half for phase3 roles

  // ---- stage W1pad (K=64): 4 tiles/wave -> 8 frags
  v8h w1r[8];
  #pragma unroll
  for (int nl = 0; nl < 4; ++nl) {
    const int n = wid*4 + nl;
    const float* src = (n < 8) ? (fW1 + (n*16+lr)*33) : (gW1 + ((n-8)*16+lr)*33);
    const float bsv  = (n < 8) ? fb1[n*16+lr] : gb1[(n-8)*16+lr];
    #pragma unroll
    for (int ks = 0; ks < 2; ++ks) {
      v8h w;
      #pragma unroll
      for (int j = 0; j < 8; ++j) {
        const int kp = ks*32 + lg*8 + j;
        float v;
        if (kp < 32)                   v = src[1+kp];
        else if (kp == 32 || kp == 34) v = src[0];
        else if (kp == 33)             v = bsv;
        else                           v = 0.f;
        w[j] = (f16)v;
      }
      w1r[nl*2+ks] = w;
    }
  }
  // ---- stage W2pad (K=160): 2 tiles/wave -> 10 frags
  v8h w2r[10];
  #pragma unroll
  for (int nl = 0; nl < 2; ++nl) {
    const int n = wid*2 + nl;
    const float* src = fW2 + (n*16+lr)*128;
    const float bsv = fb2[n*16+lr];
    #pragma unroll
    for (int ks = 0; ks < 5; ++ks) {
      v8h w;
      #pragma unroll
      for (int j = 0; j < 8; ++j) {
        const int kp = ks*32 + lg*8 + j;
        float v = (kp < 128) ? src[kp] : ((kp == 128) ? bsv : 0.f);
        w[j] = (f16)v;
      }
      w2r[nl*5+ks] = w;
    }
  }
  // ---- stage W3 (drift fW3 + diff gW2, K=160), z-half wz: 10 frags
  v8h w3d[5], w3g[5];
  {
    const float* sd = fW3 + (wz*16+lr)*128;
    const float* sg = gW2 + (wz*16+lr)*128;
    const float bd = fb3[wz*16+lr], bg = gb2[wz*16+lr];
    #pragma unroll
    for (int ks = 0; ks < 5; ++ks) {
      v8h wd, wg;
      #pragma unroll
      for (int j = 0; j < 8; ++j) {
        const int kp = ks*32 + lg*8 + j;
        wd[j] = (f16)((kp < 128) ? sd[kp] : ((kp == 128) ? bd : 0.f));
        wg[j] = (f16)((kp < 128) ? sg[kp] : ((kp == 128) ? bg : 0.f));
      }
      w3d[ks] = wd; w3g[ks] = wg;
    }
  }
  // ---- stage pWpad (K=64): 1 tile/wave -> 2 frags
  v8h pwr[2];
  {
    const float* sp = pW + (wid*16+lr)*32;
    const float bp = pb[wid*16+lr];
    #pragma unroll
    for (int ks = 0; ks < 2; ++ks) {
      v8h w;
      #pragma unroll
      for (int j = 0; j < 8; ++j) {
        const int kp = ks*32 + lg*8 + j;
        w[j] = (f16)((kp < 32) ? sp[kp] : ((kp == 33) ? bp : 0.f));
      }
      pwr[ks] = w;
    }
  }

  // ---- init LDS
  for (int i = t; i < 16*72; i += 256) Xa[i] = (f16)0.f;
  for (int i = t; i < 16*168; i += 256) {
    h1A[i] = (f16)0.f; ghA[i] = (f16)0.f; h2A[i] = (f16)0.f;
  }
  for (int i = t; i < 515; i += 256) tsL[i] = ts[i];
  __syncthreads();
  if (t < 16) {
    Xa[t*72 + 33] = (f16)1.f;
    h1A[t*168 + 128] = (f16)1.f;
    ghA[t*168 + 128] = (f16)1.f;
    h2A[t*168 + 128] = (f16)1.f;
    const float t0 = tsL[0];
    const f16 th = (f16)t0;
    Xa[t*72 + 32] = th;
    Xa[t*72 + 34] = (f16)(t0 - (float)th);
  }
  const v4f zero4 = {0.f, 0.f, 0.f, 0.f};
  v4f zm = zero4;                 // waves 0,1: z-half wid, batch lr, dims lg*4+i
  if (wid < 2) {
    zm = *(const v4f*)&z0[(r0+lr)*Z_ + wid*16 + lg*4];
    v4h a;
    #pragma unroll
    for (int i = 0; i < 4; ++i) a[i] = (f16)zm[i];
    *(v4h*)&Xa[lr*72 + wid*16 + lg*4] = a;
  }
  float loss = 0.f;
  bool pev = false, pod = false;   // deferred-proj state (for step l-1)
  int  pln = 0;
  v4f  pxv = zero4;
  __syncthreads();

  #pragma unroll 1
  for (int l = 0; l < NSTEP; ++l) {
    const float dt  = tsL[l+1] - tsL[l];
    const float sdt = sqrtf(dt);
    const int ln = l + 1;
    const bool ev = ((ln & 1) == 0) && ln >= 2 && ln <= 512;
    const bool od = ((ln & 1) == 1) && ln >= 3 && ln <= 511;

    // global loads: dW consumed at phase3 this step; xs consumed NEXT step
    // (deferred proj) -> ~full-step cover.
    v4f dwv = zero4;
    if (wid < 2) dwv = *(const v4f*)&dW[(l*B_ + r0 + lr)*Z_ + wid*16 + lg*4];
    v4f xvl = zero4;
    if (ev) xvl = *(const v4f*)&xs[(((ln-2)>>1)*B_ + r0 + lr)*D_ + wid*16 + lg*4];

    // ---- GEMM1 + deferred proj(l-1), same Xa (= z_l), same bx frags
    v4f pj = zero4;
    {
      const v8h bx0 = *(const v8h*)&Xa[lr*72 +  0 + lg*8];
      const v8h bx1 = *(const v8h*)&Xa[lr*72 + 32 + lg*8];
      #pragma unroll
      for (int nl = 0; nl < 4; ++nl) {
        v4f acc = __builtin_amdgcn_mfma_f32_16x16x32_f16(w1r[nl*2+0], bx0, zero4, 0, 0, 0);
        acc = __builtin_amdgcn_mfma_f32_16x16x32_f16(w1r[nl*2+1], bx1, acc, 0, 0, 0);
        v4h o;
        #pragma unroll
        for (int i = 0; i < 4; ++i) o[i] = (f16)fmaxf(acc[i], 0.f);
        if (wid < 2) *(v4h*)&h1A[lr*168 + (wid*4+nl)*16 + lg*4] = o;
        else         *(v4h*)&ghA[lr*168 + ((wid-2)*4+nl)*16 + lg*4] = o;
      }
      if (pev || pod) {
        pj = __builtin_amdgcn_mfma_f32_16x16x32_f16(pwr[0], bx0, zero4, 0, 0, 0);
        pj = __builtin_amdgcn_mfma_f32_16x16x32_f16(pwr[1], bx1, pj, 0, 0, 0);
      }
    }
    BAR();   // B1

    // ---- GEMM2: h2^T = W2pad @ h1pad^T (2 tiles/wave, K-chains split 3+2);
    //      deferred-proj consumption placed after MFMA issue (fills stalls).
    {
      v8h bh[5];
      #pragma unroll
      for (int ks = 0; ks < 5; ++ks) bh[ks] = *(const v8h*)&h1A[lr*168 + ks*32 + lg*8];
      v4f a0[2], a1[2];
      #pragma unroll
      for (int nl = 0; nl < 2; ++nl) {
        a0[nl] = __builtin_amdgcn_mfma_f32_16x16x32_f16(w2r[nl*5+0], bh[0], zero4, 0, 0, 0);
        a1[nl] = __builtin_amdgcn_mfma_f32_16x16x32_f16(w2r[nl*5+1], bh[1], zero4, 0, 0, 0);
        a0[nl] = __builtin_amdgcn_mfma_f32_16x16x32_f16(w2r[nl*5+2], bh[2], a0[nl], 0, 0, 0);
        a1[nl] = __builtin_amdgcn_mfma_f32_16x16x32_f16(w2r[nl*5+3], bh[3], a1[nl], 0, 0, 0);
        a0[nl] = __builtin_amdgcn_mfma_f32_16x16x32_f16(w2r[nl*5+4], bh[4], a0[nl], 0, 0, 0);
      }
      // consume deferred proj while GEMM2 chains are in flight
      if (pev) {
        #pragma unroll
        for (int i = 0; i < 4; ++i) { float d = pj[i] - pxv[i]; loss = fmaf(d, d, loss); }
      } else if (pod) {
        float* op = out + 2 + (((pln-3)>>1)*B_ + r0 + lr)*D_ + wid*16 + lg*4;
        *(f2*)&op[0] = (f2){pj[0], pj[1]};
        *(f2*)&op[2] = (f2){pj[2], pj[3]};
      }
      #pragma unroll
      for (int nl = 0; nl < 2; ++nl) {
        v4f acc = a0[nl] + a1[nl];
        v4h o;
        #pragma unroll
        for (int i = 0; i < 4; ++i) o[i] = (f16)fmaxf(acc[i], 0.f);
        *(v4h*)&h2A[lr*168 + (wid*2+nl)*16 + lg*4] = o;
      }
    }
    BAR();   // B2

    // ---- phase 3: waves 0,1 drift+diff for z-half wid (K-chains split 3+2);
    //      wave 3 writes next-step t-columns
    if (wid < 2) {
      v4f d0 = zero4, d1 = zero4, f0 = zero4, f1 = zero4;
      v8h b2f[5], bgf[5];
      #pragma unroll
      for (int ks = 0; ks < 5; ++ks) {
        b2f[ks] = *(const v8h*)&h2A[lr*168 + ks*32 + lg*8];
        bgf[ks] = *(const v8h*)&ghA[lr*168 + ks*32 + lg*8];
      }
      d0 = __builtin_amdgcn_mfma_f32_16x16x32_f16(w3d[0], b2f[0], d0, 0, 0, 0);
      f0 = __builtin_amdgcn_mfma_f32_16x16x32_f16(w3g[0], bgf[0], f0, 0, 0, 0);
      d1 = __builtin_amdgcn_mfma_f32_16x16x32_f16(w3d[1], b2f[1], d1, 0, 0, 0);
      f1 = __builtin_amdgcn_mfma_f32_16x16x32_f16(w3g[1], bgf[1], f1, 0, 0, 0);
      d0 = __builtin_amdgcn_mfma_f32_16x16x32_f16(w3d[2], b2f[2], d0, 0, 0, 0);
      f0 = __builtin_amdgcn_mfma_f32_16x16x32_f16(w3g[2], bgf[2], f0, 0, 0, 0);
      d1 = __builtin_amdgcn_mfma_f32_16x16x32_f16(w3d[3], b2f[3], d1, 0, 0, 0);
      f1 = __builtin_amdgcn_mfma_f32_16x16x32_f16(w3g[3], bgf[3], f1, 0, 0, 0);
      d0 = __builtin_amdgcn_mfma_f32_16x16x32_f16(w3d[4], b2f[4], d0, 0, 0, 0);
      f0 = __builtin_amdgcn_mfma_f32_16x16x32_f16(w3g[4], bgf[4], f0, 0, 0, 0);
      #pragma unroll
      for (int i = 0; i < 4; ++i)
        zm[i] += (d0[i] + d1[i])*dt + (f0[i] + f1[i])*(sdt*dwv[i]);
      v4h a;
      #pragma unroll
      for (int i = 0; i < 4; ++i) a[i] = (f16)zm[i];
      *(v4h*)&Xa[lr*72 + wid*16 + lg*4] = a;
    } else if (wid == 3 && lg == 0) {
      const float tn = tsL[l+1];
      const f16 th = (f16)tn;
      Xa[lr*72 + 32] = th;
      Xa[lr*72 + 34] = (f16)(tn - (float)th);
    }
    BAR();   // B3

    // hand off proj state to next iteration
    pev = ev; pod = od; pln = ln;
    if (ev) pxv = xvl;
  }
  // no epilogue needed: last proj-bearing step is l=511 (ln=512), consumed
  // at iteration 512; iterations 512/513 carry pev=pod=false forward.

  #pragma unroll
  for (int s2 = 32; s2 > 0; s2 >>= 1) loss += __shfl_down(loss, s2, 64);
  if (lane == 0) lred[wid] = loss;
  __syncthreads();
  if (t == 0)
    atomicAdd(out + 0, (lred[0] + lred[1] + lred[2] + lred[3]) * (1.f/16777216.f));
}

extern "C" void kernel_launch(void* const* d_in, const int* in_sizes, int n_in,
                              void* d_out, int out_size, void* d_ws, size_t ws_size,
                              hipStream_t stream) {
  (void)in_sizes; (void)n_in; (void)out_size; (void)ws_size;
  const float* xs   = (const float*)d_in[0];
  const float* ts   = (const float*)d_in[1];
  const float* eps  = (const float*)d_in[2];
  const float* dWp  = (const float*)d_in[3];
  const float* Wih  = (const float*)d_in[4];
  const float* Whh  = (const float*)d_in[5];
  const float* bih  = (const float*)d_in[6];
  const float* bhh  = (const float*)d_in[7];
  const float* encW = (const float*)d_in[8];
  const float* encB = (const float*)d_in[9];
  const float* qW   = (const float*)d_in[10];
  const float* qB   = (const float*)d_in[11];
  const float* fW1  = (const float*)d_in[12];
  const float* fb1  = (const float*)d_in[13];
  const float* fW2  = (const float*)d_in[14];
  const float* fb2  = (const float*)d_in[15];
  const float* fW3  = (const float*)d_in[16];
  const float* fb3  = (const float*)d_in[17];
  const float* gW1  = (const float*)d_in[18];
  const float* gb1  = (const float*)d_in[19];
  const float* gW2  = (const float*)d_in[20];
  const float* gb2  = (const float*)d_in[21];
  const float* pW   = (const float*)d_in[22];
  const float* pb   = (const float*)d_in[23];
  const float* pm   = (const float*)d_in[24];
  const float* pls  = (const float*)d_in[25];

  float* out = (float*)d_out;
  float* ws  = (float*)d_ws;
  float* hT = ws;              // 1024*128 floats
  float* z0 = ws + 131072;     // 1024*32 floats

  hipMemsetAsync(d_out, 0, 2*sizeof(float), stream);
  hipLaunchKernelGGL(gru_mfma_kernel, dim3(64), dim3(256), 0, stream,
                     xs, Wih, Whh, bih, bhh, hT);
  hipLaunchKernelGGL(enc_kernel, dim3(256), dim3(256), 0, stream,
                     hT, encW, encB, qW, qB, eps, pm, pls, z0, out);
  hipLaunchKernelGGL(sde_mfma_kernel, dim3(64), dim3(256), 0, stream,
                     z0, ts, dWp, xs, fW1, fb1, fW2, fb2, fW3, fb3,
                     gW1, gb1, gW2, gb2, pW, pb, out);
}